// Round 17
// baseline (131.485 us; speedup 1.0000x reference)
//
#include <hip/hip_runtime.h>
#include <hip/hip_bf16.h>

using short4v = __attribute__((ext_vector_type(4))) short;
using short8 = __attribute__((ext_vector_type(8))) short;
using f32x4  = __attribute__((ext_vector_type(4))) float;
using f32x16 = __attribute__((ext_vector_type(16))) float;
using int4v  = __attribute__((ext_vector_type(4))) int;

#define T_SEQ  2048
#define C_DIM  2048
#define NH     32
#define NKV    8
#define HD     64
#define WINDOW 512
#define NGLOB  16
#define KLOG   0.180336880f   // 0.125 * log2(e)

__device__ inline ushort f2bf(float f) {
  union { float f; unsigned u; } v; v.f = f;
  unsigned u = v.u;
  u += 0x7fffu + ((u >> 16) & 1u);
  return (ushort)(u >> 16);
}
__device__ inline float bf2f(ushort h) {
  union { unsigned u; float f; } v; v.u = ((unsigned)h) << 16;
  return v.f;
}
__device__ inline float max3f(float a, float b, float c) { return fmaxf(fmaxf(a, b), c); }

__device__ __forceinline__ void gl_lds16(const ushort* g, ushort* l) {
  __builtin_amdgcn_global_load_lds(
      (const __attribute__((address_space(1))) void*)g,
      (__attribute__((address_space(3))) void*)l, 16, 0, 0);
}

__device__ __forceinline__ f32x16 zero16() {
  f32x16 v;
#pragma unroll
  for (int i = 0; i < 16; i++) v[i] = 0.f;
  return v;
}

__device__ __forceinline__ short8 cvt8(f32x4 a, f32x4 b) {
  unsigned w0, w1, w2, w3;
  asm("v_cvt_pk_bf16_f32 %0, %1, %2" : "=v"(w0) : "v"(a[0]), "v"(a[1]));
  asm("v_cvt_pk_bf16_f32 %0, %1, %2" : "=v"(w1) : "v"(a[2]), "v"(a[3]));
  asm("v_cvt_pk_bf16_f32 %0, %1, %2" : "=v"(w2) : "v"(b[0]), "v"(b[1]));
  asm("v_cvt_pk_bf16_f32 %0, %1, %2" : "=v"(w3) : "v"(b[2]), "v"(b[3]));
  int4v w = { (int)w0, (int)w1, (int)w2, (int)w3 };
  return __builtin_bit_cast(short8, w);
}

// One fused f32->bf16 convert over 5 segments (8 elems per chunk).
__global__ void cvt_all(const float* __restrict__ s0, ushort* __restrict__ d0, int n0,
                        const float* __restrict__ s1, ushort* __restrict__ d1, int n1,
                        const float* __restrict__ s2, ushort* __restrict__ d2, int n2,
                        const float* __restrict__ s3, ushort* __restrict__ d3, int n3,
                        const float* __restrict__ s4, ushort* __restrict__ d4, int n4) {
  int total = n0 + n1 + n2 + n3 + n4;
  int stride = gridDim.x * blockDim.x;
  for (int i = blockIdx.x * blockDim.x + threadIdx.x; i < total; i += stride) {
    int j = i; const float* s; ushort* d;
    if (j < n0) { s = s0; d = d0; }
    else { j -= n0;
      if (j < n1) { s = s1; d = d1; }
      else { j -= n1;
        if (j < n2) { s = s2; d = d2; }
        else { j -= n2;
          if (j < n3) { s = s3; d = d3; }
          else { j -= n3; s = s4; d = d4; } } } }
    f32x4 a = *reinterpret_cast<const f32x4*>(s + (size_t)j * 8);
    f32x4 b = *reinterpret_cast<const f32x4*>(s + (size_t)j * 8 + 4);
    *reinterpret_cast<short8*>(d + (size_t)j * 8) = cvt8(a, b);
  }
}

// QKV GEMM (unchanged): 128x64 tile, BK=64, 4 waves, XCD rect swizzle,
// RoPE(Q,K)+Q-scale fused epilogue, V stored transposed.
template <int MODE>
__global__ __launch_bounds__(256) void gemm2p(const ushort* __restrict__ A,
                                              const ushort* __restrict__ B0,
                                              const ushort* __restrict__ B1,
                                              const ushort* __restrict__ B2,
                                              void* __restrict__ C0,
                                              void* __restrict__ C1,
                                              void* __restrict__ C2,
                                              const float* __restrict__ fc,
                                              const float* __restrict__ fs,
                                              int K) {
  __shared__ ushort As[2][2][128][32];
  __shared__ ushort Bs[2][2][64][32];
  const int tid  = threadIdx.x;
  const int lane = tid & 63;
  const int wid  = tid >> 6;
  const int wr = wid >> 1, wc = wid & 1;
  const int r16 = lane & 15, g16 = (lane >> 4) & 3;

  int id = blockIdx.x + blockIdx.y * gridDim.x;
  int c8 = id & 7, rr = id >> 3;
  int bx, by;
  if constexpr (MODE == 1) { bx = (c8 & 3) * 12 + (rr % 12); by = (c8 >> 2) * 8 + rr / 12; }
  else                     { bx = (c8 & 3) * 8  + (rr % 8);  by = (c8 >> 2) * 8 + rr / 8; }

  const ushort* Brow;
  void* Cout;
  int ldc, col0;
  bool vtr = false;
  if constexpr (MODE == 1) {
    if (bx < 32)      { Brow = B0 + (size_t)bx * 64 * K;        Cout = C0; ldc = 2048; col0 = bx * 64; }
    else if (bx < 40) { Brow = B1 + (size_t)(bx - 32) * 64 * K; Cout = C1; ldc = 512;  col0 = (bx - 32) * 64; }
    else              { Brow = B2 + (size_t)(bx - 40) * 64 * K; Cout = C2; ldc = 512;  col0 = (bx - 40) * 64; vtr = true; }
  } else {
    Brow = B0 + (size_t)bx * 64 * K; Cout = C0; ldc = 2048; col0 = bx * 64;
  }
  const ushort* Arow = A + (size_t)by * 128 * K;

  f32x4 acc[4][2];
#pragma unroll
  for (int i = 0; i < 4; i++)
#pragma unroll
    for (int j = 0; j < 2; j++) acc[i][j] = (f32x4){0.f, 0.f, 0.f, 0.f};

  const int srow = tid >> 2, scch = tid & 3;
  const int ssc  = scch ^ ((srow >> 1) & 3);
  const int rchunk = (g16 ^ ((r16 >> 1) & 3)) * 8;

  const int nt = K >> 6;
  int d = 0;

#define STAGE(dd, k0)                                                               \
  {                                                                                 \
    gl_lds16(&Arow[(size_t)srow * K + (k0) + ssc * 8],             &As[dd][0][srow][scch * 8]);      \
    gl_lds16(&Arow[(size_t)(srow + 64) * K + (k0) + ssc * 8],      &As[dd][0][srow + 64][scch * 8]); \
    gl_lds16(&Arow[(size_t)srow * K + (k0) + 32 + ssc * 8],        &As[dd][1][srow][scch * 8]);      \
    gl_lds16(&Arow[(size_t)(srow + 64) * K + (k0) + 32 + ssc * 8], &As[dd][1][srow + 64][scch * 8]); \
    gl_lds16(&Brow[(size_t)srow * K + (k0) + ssc * 8],             &Bs[dd][0][srow][scch * 8]);      \
    gl_lds16(&Brow[(size_t)srow * K + (k0) + 32 + ssc * 8],        &Bs[dd][1][srow][scch * 8]);      \
  }

  STAGE(0, 0);
  __syncthreads();

  for (int t = 0; t < nt; ++t) {
    if (t + 1 < nt) STAGE(d ^ 1, (t + 1) * 64);
#pragma unroll
    for (int kk = 0; kk < 2; kk++) {
      short8 af[4], bfv[2];
#pragma unroll
      for (int i = 0; i < 4; i++)
        af[i] = *reinterpret_cast<const short8*>(&As[d][kk][wr * 64 + i * 16 + r16][rchunk]);
#pragma unroll
      for (int j = 0; j < 2; j++)
        bfv[j] = *reinterpret_cast<const short8*>(&Bs[d][kk][wc * 32 + j * 16 + r16][rchunk]);
#pragma unroll
      for (int i = 0; i < 4; i++)
#pragma unroll
        for (int j = 0; j < 2; j++)
          acc[i][j] = __builtin_amdgcn_mfma_f32_16x16x32_bf16(af[i], bfv[j], acc[i][j], 0, 0, 0);
    }
    __syncthreads();
    d ^= 1;
  }
#undef STAGE

  const bool doRope = (MODE == 1) && !vtr;
  const float ksc = (MODE == 1 && bx < 32) ? KLOG : 1.0f;

#pragma unroll
  for (int i = 0; i < 4; i++)
#pragma unroll
    for (int j = 0; j < 2; j++) {
      int col = col0 + wc * 32 + j * 16 + r16;
      int row0 = by * 128 + wr * 64 + i * 16 + g16 * 4;
      if (MODE == 1 && vtr) {
        short4v tv;
#pragma unroll
        for (int r = 0; r < 4; r++) tv[r] = (short)f2bf(acc[i][j][r]);
        *reinterpret_cast<short4v*>(&((ushort*)Cout)[(size_t)col * T_SEQ + row0]) = tv;
      } else if (doRope) {
        int pr = (col & 63) >> 1;
        bool ev = ((col & 1) == 0);
#pragma unroll
        for (int r = 0; r < 4; r++) {
          float a = acc[i][j][r];
          float b = __shfl_xor(a, 1);
          int t = row0 + r;
          float cv = fc[t * 32 + pr], sv = fs[t * 32 + pr];
          float v = ev ? (a * cv - b * sv) : (b * sv + a * cv);
          ((ushort*)Cout)[(size_t)t * ldc + col] = f2bf(v * ksc);
        }
      } else {
#pragma unroll
        for (int r = 0; r < 4; r++) {
          if constexpr (MODE == 0) ((float*)Cout)[(size_t)(row0 + r) * ldc + col] = acc[i][j][r];
          else                     ((ushort*)Cout)[(size_t)(row0 + r) * ldc + col] = f2bf(acc[i][j][r]);
        }
      }
    }
}

// O-projection, split-K=2: 128x128 tile, nt=16 per block, 512 blocks all
// co-resident (2/CU at 64 KB LDS). Latency-model test: halving the per-block
// serial K-chain should halve duration. f32 atomic accumulate into zeroed out.
__global__ __launch_bounds__(512) void gemm128s(const ushort* __restrict__ A,
                                                const ushort* __restrict__ B,
                                                float* __restrict__ C,
                                                int K) {
  __shared__ ushort As[2][2][128][32];
  __shared__ ushort Bs[2][2][128][32];
  const int tid  = threadIdx.x;
  const int lane = tid & 63;
  const int wid  = tid >> 6;             // 0..7
  const int wr = wid >> 2, wc = wid & 3; // 2M x 4N, wave = 64x32
  const int r16 = lane & 15, g16 = (lane >> 4) & 3;

  // XCD rect swizzle; both K-splits of a tile land on the same XCD.
  int id = blockIdx.x;
  int c8 = id & 7, rr = id >> 3;         // rr 0..63
  int ks = rr & 1, t8 = rr >> 1;         // 32 tiles per XCD
  int bx = (c8 & 3) * 4 + (t8 & 3), by = (c8 >> 2) * 8 + (t8 >> 2);
  const int kbase = ks * (K >> 1);

  const ushort* Arow = A + (size_t)by * 128 * K + kbase;
  const ushort* Brow = B + (size_t)bx * 128 * K + kbase;

  f32x4 acc[4][2];
#pragma unroll
  for (int i = 0; i < 4; i++)
#pragma unroll
    for (int j = 0; j < 2; j++) acc[i][j] = (f32x4){0.f, 0.f, 0.f, 0.f};

  const int srow = tid >> 2, scch = tid & 3;   // 128 rows x 4 chunks
  const int ssc  = scch ^ ((srow >> 1) & 3);
  const int rchunk = (g16 ^ ((r16 >> 1) & 3)) * 8;

  const int nt = K >> 7;                 // 16 iterations (half-K)
  int d = 0;

#define STAGE(dd, k0)                                                          \
  {                                                                            \
    gl_lds16(&Arow[(size_t)srow * K + (k0) + ssc * 8],      &As[dd][0][srow][scch * 8]); \
    gl_lds16(&Arow[(size_t)srow * K + (k0) + 32 + ssc * 8], &As[dd][1][srow][scch * 8]); \
    gl_lds16(&Brow[(size_t)srow * K + (k0) + ssc * 8],      &Bs[dd][0][srow][scch * 8]); \
    gl_lds16(&Brow[(size_t)srow * K + (k0) + 32 + ssc * 8], &Bs[dd][1][srow][scch * 8]); \
  }

  STAGE(0, 0);
  asm volatile("s_waitcnt vmcnt(0)" ::: "memory");
  __builtin_amdgcn_s_barrier();

  for (int t = 0; t < nt; ++t) {
    if (t + 1 < nt) {
      STAGE(d ^ 1, (t + 1) * 64);
      asm volatile("s_waitcnt vmcnt(4)" ::: "memory");
    } else {
      asm volatile("s_waitcnt vmcnt(0)" ::: "memory");
    }
    __builtin_amdgcn_s_barrier();
#pragma unroll
    for (int kk = 0; kk < 2; kk++) {
      short8 af[4], bfv[2];
#pragma unroll
      for (int i = 0; i < 4; i++)
        af[i] = *reinterpret_cast<const short8*>(&As[d][kk][wr * 64 + i * 16 + r16][rchunk]);
#pragma unroll
      for (int j = 0; j < 2; j++)
        bfv[j] = *reinterpret_cast<const short8*>(&Bs[d][kk][wc * 32 + j * 16 + r16][rchunk]);
#pragma unroll
      for (int i = 0; i < 4; i++)
#pragma unroll
        for (int j = 0; j < 2; j++)
          acc[i][j] = __builtin_amdgcn_mfma_f32_16x16x32_bf16(af[i], bfv[j], acc[i][j], 0, 0, 0);
    }
    asm volatile("" ::: "memory");
    __builtin_amdgcn_s_barrier();
    d ^= 1;
  }
#undef STAGE

#pragma unroll
  for (int i = 0; i < 4; i++)
#pragma unroll
    for (int j = 0; j < 2; j++) {
      int col = bx * 128 + wc * 32 + j * 16 + r16;
      int row0 = by * 128 + wr * 64 + i * 16 + g16 * 4;
#pragma unroll
      for (int r = 0; r < 4; r++)
        unsafeAtomicAdd(&C[(size_t)(row0 + r) * C_DIM + col], acc[i][j][r]);
    }
}

// Flash attention, swapped-operand 32x32, block-staged K/V in LDS,
// counted-vmcnt pipeline. (unchanged)
__global__ __launch_bounds__(512) void attn32(const ushort* __restrict__ Q,
                                              const ushort* __restrict__ K,
                                              const ushort* __restrict__ Vt,
                                              ushort* __restrict__ Y) {
  __shared__ ushort Klds[2][2][2048];
  __shared__ ushort Vlds[2][2][2048];
  __shared__ float oS[4][64][33];
  __shared__ float mS[4][32];
  __shared__ float sS[4][64];
  ushort (*Ot)[32][72] = reinterpret_cast<ushort (*)[32][72]>(&oS[0][0][0]);
  const int tid  = threadIdx.x;
  const int lane = tid & 63;
  const int wv   = tid >> 6;
  const int hh   = wv & 3;
  const int split = wv >> 2;
  const int g  = blockIdx.x & 7;
  const int qt = 63 - (blockIdx.x >> 3);
  const int h  = g * 4 + hh;
  const int q0 = qt << 5;
  const int l31 = lane & 31, hi = lane >> 5;
  const int hi8 = hi << 3, hi4 = hi << 2;
  const int qrow = q0 + l31;

  short8 qf[4];
#pragma unroll
  for (int s = 0; s < 4; s++)
    qf[s] = *reinterpret_cast<const short8*>(&Q[(size_t)qrow * C_DIM + h * HD + s * 16 + hi8]);

  f32x16 o[2] = { zero16(), zero16() };
  f32x16 sacc = zero16();
  float mrow = -1e30f;
  short8 ones8;
#pragma unroll
  for (int s = 0; s < 8; s++) ones8[s] = (short)0x3F80;

  auto pack8 = [&](const float* pp) -> short8 {
    unsigned wA, wB, wC, wD;
    asm("v_cvt_pk_bf16_f32 %0, %1, %2" : "=v"(wA) : "v"(pp[0]), "v"(pp[1]));
    asm("v_cvt_pk_bf16_f32 %0, %1, %2" : "=v"(wB) : "v"(pp[2]), "v"(pp[3]));
    asm("v_cvt_pk_bf16_f32 %0, %1, %2" : "=v"(wC) : "v"(pp[4]), "v"(pp[5]));
    asm("v_cvt_pk_bf16_f32 %0, %1, %2" : "=v"(wD) : "v"(pp[6]), "v"(pp[7]));
    asm("v_permlane32_swap_b32 %0, %1" : "+v"(wA), "+v"(wC));
    asm("v_permlane32_swap_b32 %0, %1" : "+v"(wB), "+v"(wD));
    int4v w4 = { (int)wA, (int)wB, (int)wC, (int)wD };
    return __builtin_bit_cast(short8, w4);
  };

  int wsr = (q0 - (WINDOW - 1)) >> 5;
  int wstart = (wsr < 1) ? 32 : (wsr << 5);
  int ntw = (q0 >= wstart) ? (((q0 - wstart) >> 5) + 1) : 0;
  const int NT = 1 + ntw;
  const int ihalf = (NT + 1) >> 1;

#define KBOF(i) ((i) == 0 ? 0 : wstart + ((i) - 1) * 32)
#define MSK(i)  ((i) == 0 || (KBOF(i) < q0 - 480) || (KBOF(i) == q0))

  const int sp_s = tid >> 8;
  const int kr = (tid >> 3) & 31, kc = tid & 7;
  const int vr = (tid >> 2) & 63, vc = tid & 3;
  const ushort* ksrc0 = K + (size_t)kr * (NKV * HD) + g * HD + ((kc ^ (kr & 7)) * 8);
  const ushort* vsrc0 = Vt + (size_t)(g * HD + vr) * T_SEQ + ((vc ^ ((vr >> 1) & 3)) * 8);
  ushort* kdst[2] = { &Klds[sp_s][0][(tid & 255) * 8], &Klds[sp_s][1][(tid & 255) * 8] };
  ushort* vdst[2] = { &Vlds[sp_s][0][(tid & 255) * 8], &Vlds[sp_s][1][(tid & 255) * 8] };

#define STAGE(dd, i0t, i1t)                                                    \
  {                                                                            \
    int idxs = sp_s ? (i1t) : (i0t);                                           \
    if (idxs > NT - 1) idxs = NT - 1;                                          \
    int kbs = KBOF(idxs);                                                      \
    gl_lds16(ksrc0 + (size_t)kbs * (NKV * HD), kdst[dd]);                      \
    gl_lds16(vsrc0 + kbs, vdst[dd]);                                           \
  }

#define PROCESS(dd, kb, domask)                                                    \
  {                                                                                \
    short8 kf0 = *reinterpret_cast<const short8*>(                                 \
        &Klds[split][dd][l31 * 64 + (((0 * 2 + hi) ^ (l31 & 7)) * 8)]);            \
    short8 kf1 = *reinterpret_cast<const short8*>(                                 \
        &Klds[split][dd][l31 * 64 + (((1 * 2 + hi) ^ (l31 & 7)) * 8)]);            \
    short8 kf2 = *reinterpret_cast<const short8*>(                                 \
        &Klds[split][dd][l31 * 64 + (((2 * 2 + hi) ^ (l31 & 7)) * 8)]);            \
    short8 kf3 = *reinterpret_cast<const short8*>(                                 \
        &Klds[split][dd][l31 * 64 + (((3 * 2 + hi) ^ (l31 & 7)) * 8)]);            \
    f32x16 sa = zero16();                                                          \
    __builtin_amdgcn_s_setprio(1);                                                 \
    sa = __builtin_amdgcn_mfma_f32_32x32x16_bf16(kf0, qf[0], sa, 0, 0, 0);         \
    sa = __builtin_amdgcn_mfma_f32_32x32x16_bf16(kf1, qf[1], sa, 0, 0, 0);         \
    sa = __builtin_amdgcn_mfma_f32_32x32x16_bf16(kf2, qf[2], sa, 0, 0, 0);         \
    sa = __builtin_amdgcn_mfma_f32_32x32x16_bf16(kf3, qf[3], sa, 0, 0, 0);         \
    __builtin_amdgcn_s_setprio(0);                                                 \
    float p[16];                                                                   \
    _Pragma("unroll") for (int r = 0; r < 16; r++) p[r] = sa[r];                   \
    if (domask) {                                                                  \
      _Pragma("unroll") for (int r = 0; r < 16; r++) {                             \
        int kidx = (kb) + (r & 3) + 8 * (r >> 2) + hi4;                            \
        bool ok = ((kidx <= qrow) && (kidx >= qrow - (WINDOW - 1))) || (kidx < NGLOB); \
        p[r] = ok ? p[r] : -1e30f;                                                 \
      }                                                                            \
    }                                                                              \
    float m0 = max3f(p[0], p[1], p[2]);                                            \
    float m1 = max3f(p[3], p[4], p[5]);                                            \
    float m2 = max3f(p[6], p[7], p[8]);                                            \
    float m3 = max3f(p[9], p[10], p[11]);                                          \
    float m4 = max3f(p[12], p[13], p[14]);                                         \
    float tmax = fmaxf(max3f(m0, m1, m2), max3f(m3, m4, p[15]));                   \
    float pmax = fmaxf(tmax, __shfl_xor(tmax, 32));                                \
    if (!__all(pmax <= mrow + 8.0f)) {                                             \
      float mnew = fmaxf(mrow, pmax);                                              \
      float corr = exp2f(mrow - mnew);                                             \
      sacc[0] *= corr;                                                             \
      _Pragma("unroll") for (int r = 0; r < 16; r++) { o[0][r] *= corr; o[1][r] *= corr; } \
      mrow = mnew;                                                                 \
    }                                                                              \
    _Pragma("unroll") for (int r = 0; r < 16; r++) p[r] = exp2f(p[r] - mrow);      \
    short8 pb0 = pack8(&p[0]);                                                     \
    short8 pb1 = pack8(&p[8]);                                                     \
    short8 v0 = *reinterpret_cast<const short8*>(                                  \
        &Vlds[split][dd][(0 * 32 + l31) * 32 + (((0 * 2 + hi) ^ ((l31 >> 1) & 3)) * 8)]); \
    short8 v1 = *reinterpret_cast<const short8*>(                                  \
        &Vlds[split][dd][(0 * 32 + l31) * 32 + (((1 * 2 + hi) ^ ((l31 >> 1) & 3)) * 8)]); \
    short8 v2 = *reinterpret_cast<const short8*>(                                  \
        &Vlds[split][dd][(1 * 32 + l31) * 32 + (((0 * 2 + hi) ^ (((32 + l31) >> 1) & 3)) * 8)]); \
    short8 v3 = *reinterpret_cast<const short8*>(                                  \
        &Vlds[split][dd][(1 * 32 + l31) * 32 + (((1 * 2 + hi) ^ (((32 + l31) >> 1) & 3)) * 8)]); \
    __builtin_amdgcn_s_setprio(1);                                                 \
    sacc = __builtin_amdgcn_mfma_f32_32x32x16_bf16(ones8, pb0, sacc, 0, 0, 0);     \
    sacc = __builtin_amdgcn_mfma_f32_32x32x16_bf16(ones8, pb1, sacc, 0, 0, 0);     \
    o[0] = __builtin_amdgcn_mfma_f32_32x32x16_bf16(v0, pb0, o[0], 0, 0, 0);        \
    o[0] = __builtin_amdgcn_mfma_f32_32x32x16_bf16(v1, pb1, o[0], 0, 0, 0);        \
    o[1] = __builtin_amdgcn_mfma_f32_32x32x16_bf16(v2, pb0, o[1], 0, 0, 0);        \
    o[1] = __builtin_amdgcn_mfma_f32_32x32x16_bf16(v3, pb1, o[1], 0, 0, 0);        \
    __builtin_amdgcn_s_setprio(0);                                                 \
  }

  STAGE(0, 0, ihalf);
  asm volatile("s_waitcnt vmcnt(0)" ::: "memory");
  __builtin_amdgcn_s_barrier();
  int d = 0;
  for (int it = 0; it < ihalf; ++it) {
    if (it + 1 < ihalf) {
      STAGE(d ^ 1, it + 1, ihalf + it + 1);
      asm volatile("s_waitcnt vmcnt(2)" ::: "memory");
    } else {
      asm volatile("s_waitcnt vmcnt(0)" ::: "memory");
    }
    __builtin_amdgcn_s_barrier();
    int idx = split ? (ihalf + it) : it;
    if (idx < NT) {
      int kb = KBOF(idx);
      PROCESS(d, kb, MSK(idx));
    }
    asm volatile("" ::: "memory");
    __builtin_amdgcn_s_barrier();
    d ^= 1;
  }
#undef STAGE
#undef PROCESS
#undef KBOF
#undef MSK

  float ssum = sacc[0];

  if (split == 1) {
    if (hi == 0) mS[hh][l31] = mrow;
    sS[hh][lane] = ssum;
#pragma unroll
    for (int ntl = 0; ntl < 2; ntl++)
#pragma unroll
      for (int r = 0; r < 16; r++) oS[hh][lane][ntl * 16 + r] = o[ntl][r];
  }
  __syncthreads();

  float inv = 0.f;
  if (split == 0) {
    float mB = mS[hh][l31];
    float sB = sS[hh][lane];
    float mN = fmaxf(mrow, mB);
    float cA = exp2f(mrow - mN), cB = exp2f(mB - mN);
    ssum = ssum * cA + sB * cB;
#pragma unroll
    for (int ntl = 0; ntl < 2; ntl++)
#pragma unroll
      for (int r = 0; r < 16; r++)
        o[ntl][r] = o[ntl][r] * cA + oS[hh][lane][ntl * 16 + r] * cB;
    inv = 1.0f / ssum;
  }
  __syncthreads();

  if (split == 0) {
#pragma unroll
    for (int ntl = 0; ntl < 2; ntl++)
#pragma unroll
      for (int r = 0; r < 16; r++) {
        int dim = ntl * 32 + (r & 3) + 8 * (r >> 2) + hi4;
        Ot[hh][l31][dim] = f2bf(o[ntl][r] * inv);
      }
  }
  __syncthreads();

  if (split == 0) {
    int qq = lane >> 1, hf = lane & 1;
#pragma unroll
    for (int c = 0; c < 4; c++) {
      short8 vv = *reinterpret_cast<const short8*>(&Ot[hh][qq][hf * 32 + c * 8]);
      *reinterpret_cast<short8*>(&Y[(size_t)(q0 + qq) * C_DIM + h * HD + hf * 32 + c * 8]) = vv;
    }
  }
}

extern "C" void kernel_launch(void* const* d_in, const int* in_sizes, int n_in,
                              void* d_out, int out_size, void* d_ws, size_t ws_size,
                              hipStream_t stream) {
  const float* x  = (const float*)d_in[0];
  const float* fc = (const float*)d_in[1];
  const float* fs = (const float*)d_in[2];
  const float* wq = (const float*)d_in[3];
  const float* wk = (const float*)d_in[4];
  const float* wv = (const float*)d_in[5];
  const float* wo = (const float*)d_in[6];
  float* out = (float*)d_out;

  const size_t SZ_X = (size_t)T_SEQ * C_DIM;
  const size_t SZ_W = (size_t)(NKV * HD) * C_DIM;

  ushort* xb  = (ushort*)d_ws;
  ushort* wqb = xb  + SZ_X;
  ushort* wkb = wqb + SZ_X;
  ushort* wvb = wkb + SZ_W;
  ushort* wob = wvb + SZ_W;
  ushort* Qb  = wob + SZ_X;
  ushort* Kb  = Qb  + SZ_X;
  ushort* Vt  = Kb  + SZ_W;
  ushort* Yb  = Vt  + SZ_W;

  cvt_all<<<1024, 256, 0, stream>>>(x,  xb,  (int)(SZ_X / 8),
                                    wq, wqb, (int)(SZ_X / 8),
                                    wk, wkb, (int)(SZ_W / 8),
                                    wv, wvb, (int)(SZ_W / 8),
                                    wo, wob, (int)(SZ_X / 8));

  // fused QKV projection + RoPE(Q,K) + Q-scale; V written pre-transposed
  gemm2p<1><<<dim3(48, 16), 256, 0, stream>>>(xb, wqb, wkb, wvb, Qb, Kb, Vt, fc, fs, C_DIM);

  // zero the output for split-K atomic accumulation (overlaps nothing critical)
  hipMemsetAsync(out, 0, (size_t)out_size * sizeof(float), stream);

  attn32<<<512, 512, 0, stream>>>(Qb, Kb, Vt, Yb);

  // output projection, split-K=2, atomic f32 accumulate
  gemm128s<<<512, 512, 0, stream>>>(Yb, wob, out, C_DIM);
}

// Round 18
// 116.056 us; speedup vs baseline: 1.1329x; 1.1329x over previous
//
#include <hip/hip_runtime.h>
#include <hip/hip_bf16.h>

using short4v = __attribute__((ext_vector_type(4))) short;
using short8 = __attribute__((ext_vector_type(8))) short;
using f32x4  = __attribute__((ext_vector_type(4))) float;
using f32x16 = __attribute__((ext_vector_type(16))) float;
using int4v  = __attribute__((ext_vector_type(4))) int;

#define T_SEQ  2048
#define C_DIM  2048
#define NH     32
#define NKV    8
#define HD     64
#define WINDOW 512
#define NGLOB  16
#define KLOG   0.180336880f   // 0.125 * log2(e)

__device__ inline ushort f2bf(float f) {
  union { float f; unsigned u; } v; v.f = f;
  unsigned u = v.u;
  u += 0x7fffu + ((u >> 16) & 1u);
  return (ushort)(u >> 16);
}
__device__ inline float bf2f(ushort h) {
  union { unsigned u; float f; } v; v.u = ((unsigned)h) << 16;
  return v.f;
}
__device__ inline float max3f(float a, float b, float c) { return fmaxf(fmaxf(a, b), c); }

__device__ __forceinline__ void gl_lds16(const ushort* g, ushort* l) {
  __builtin_amdgcn_global_load_lds(
      (const __attribute__((address_space(1))) void*)g,
      (__attribute__((address_space(3))) void*)l, 16, 0, 0);
}

__device__ __forceinline__ f32x16 zero16() {
  f32x16 v;
#pragma unroll
  for (int i = 0; i < 16; i++) v[i] = 0.f;
  return v;
}

__device__ __forceinline__ short8 cvt8(f32x4 a, f32x4 b) {
  unsigned w0, w1, w2, w3;
  asm("v_cvt_pk_bf16_f32 %0, %1, %2" : "=v"(w0) : "v"(a[0]), "v"(a[1]));
  asm("v_cvt_pk_bf16_f32 %0, %1, %2" : "=v"(w1) : "v"(a[2]), "v"(a[3]));
  asm("v_cvt_pk_bf16_f32 %0, %1, %2" : "=v"(w2) : "v"(b[0]), "v"(b[1]));
  asm("v_cvt_pk_bf16_f32 %0, %1, %2" : "=v"(w3) : "v"(b[2]), "v"(b[3]));
  int4v w = { (int)w0, (int)w1, (int)w2, (int)w3 };
  return __builtin_bit_cast(short8, w);
}

// One fused f32->bf16 convert over 5 segments (8 elems per chunk).
__global__ void cvt_all(const float* __restrict__ s0, ushort* __restrict__ d0, int n0,
                        const float* __restrict__ s1, ushort* __restrict__ d1, int n1,
                        const float* __restrict__ s2, ushort* __restrict__ d2, int n2,
                        const float* __restrict__ s3, ushort* __restrict__ d3, int n3,
                        const float* __restrict__ s4, ushort* __restrict__ d4, int n4) {
  int total = n0 + n1 + n2 + n3 + n4;
  int stride = gridDim.x * blockDim.x;
  for (int i = blockIdx.x * blockDim.x + threadIdx.x; i < total; i += stride) {
    int j = i; const float* s; ushort* d;
    if (j < n0) { s = s0; d = d0; }
    else { j -= n0;
      if (j < n1) { s = s1; d = d1; }
      else { j -= n1;
        if (j < n2) { s = s2; d = d2; }
        else { j -= n2;
          if (j < n3) { s = s3; d = d3; }
          else { j -= n3; s = s4; d = d4; } } } }
    f32x4 a = *reinterpret_cast<const f32x4*>(s + (size_t)j * 8);
    f32x4 b = *reinterpret_cast<const f32x4*>(s + (size_t)j * 8 + 4);
    *reinterpret_cast<short8*>(d + (size_t)j * 8) = cvt8(a, b);
  }
}

// 2-phase double-buffered bf16 GEMM, C = A @ B^T, 128x64 tile, BK=64, 4 waves,
// XCD rect swizzle. MODE 0: plain f32 out (grid 32x16; rect 8x8).
// MODE 1: fused QKV (grid 48x16; rect 12x8); RoPE(Q,K)+Q-scale fused epilogue
// via shfl_xor pair exchange; V region stores transposed.
template <int MODE>
__global__ __launch_bounds__(256) void gemm2p(const ushort* __restrict__ A,
                                              const ushort* __restrict__ B0,
                                              const ushort* __restrict__ B1,
                                              const ushort* __restrict__ B2,
                                              void* __restrict__ C0,
                                              void* __restrict__ C1,
                                              void* __restrict__ C2,
                                              const float* __restrict__ fc,
                                              const float* __restrict__ fs,
                                              int K) {
  __shared__ ushort As[2][2][128][32];
  __shared__ ushort Bs[2][2][64][32];
  const int tid  = threadIdx.x;
  const int lane = tid & 63;
  const int wid  = tid >> 6;
  const int wr = wid >> 1, wc = wid & 1;
  const int r16 = lane & 15, g16 = (lane >> 4) & 3;

  int id = blockIdx.x + blockIdx.y * gridDim.x;
  int c8 = id & 7, rr = id >> 3;
  int bx, by;
  if constexpr (MODE == 1) { bx = (c8 & 3) * 12 + (rr % 12); by = (c8 >> 2) * 8 + rr / 12; }
  else                     { bx = (c8 & 3) * 8  + (rr % 8);  by = (c8 >> 2) * 8 + rr / 8; }

  const ushort* Brow;
  void* Cout;
  int ldc, col0;
  bool vtr = false;
  if constexpr (MODE == 1) {
    if (bx < 32)      { Brow = B0 + (size_t)bx * 64 * K;        Cout = C0; ldc = 2048; col0 = bx * 64; }
    else if (bx < 40) { Brow = B1 + (size_t)(bx - 32) * 64 * K; Cout = C1; ldc = 512;  col0 = (bx - 32) * 64; }
    else              { Brow = B2 + (size_t)(bx - 40) * 64 * K; Cout = C2; ldc = 512;  col0 = (bx - 40) * 64; vtr = true; }
  } else {
    Brow = B0 + (size_t)bx * 64 * K; Cout = C0; ldc = 2048; col0 = bx * 64;
  }
  const ushort* Arow = A + (size_t)by * 128 * K;

  f32x4 acc[4][2];
#pragma unroll
  for (int i = 0; i < 4; i++)
#pragma unroll
    for (int j = 0; j < 2; j++) acc[i][j] = (f32x4){0.f, 0.f, 0.f, 0.f};

  const int srow = tid >> 2, scch = tid & 3;
  const int ssc  = scch ^ ((srow >> 1) & 3);
  const int rchunk = (g16 ^ ((r16 >> 1) & 3)) * 8;

  const int nt = K >> 6;
  int d = 0;

#define STAGE(dd, k0)                                                               \
  {                                                                                 \
    gl_lds16(&Arow[(size_t)srow * K + (k0) + ssc * 8],             &As[dd][0][srow][scch * 8]);      \
    gl_lds16(&Arow[(size_t)(srow + 64) * K + (k0) + ssc * 8],      &As[dd][0][srow + 64][scch * 8]); \
    gl_lds16(&Arow[(size_t)srow * K + (k0) + 32 + ssc * 8],        &As[dd][1][srow][scch * 8]);      \
    gl_lds16(&Arow[(size_t)(srow + 64) * K + (k0) + 32 + ssc * 8], &As[dd][1][srow + 64][scch * 8]); \
    gl_lds16(&Brow[(size_t)srow * K + (k0) + ssc * 8],             &Bs[dd][0][srow][scch * 8]);      \
    gl_lds16(&Brow[(size_t)srow * K + (k0) + 32 + ssc * 8],        &Bs[dd][1][srow][scch * 8]);      \
  }

  STAGE(0, 0);
  __syncthreads();

  for (int t = 0; t < nt; ++t) {
    if (t + 1 < nt) STAGE(d ^ 1, (t + 1) * 64);
#pragma unroll
    for (int kk = 0; kk < 2; kk++) {
      short8 af[4], bfv[2];
#pragma unroll
      for (int i = 0; i < 4; i++)
        af[i] = *reinterpret_cast<const short8*>(&As[d][kk][wr * 64 + i * 16 + r16][rchunk]);
#pragma unroll
      for (int j = 0; j < 2; j++)
        bfv[j] = *reinterpret_cast<const short8*>(&Bs[d][kk][wc * 32 + j * 16 + r16][rchunk]);
#pragma unroll
      for (int i = 0; i < 4; i++)
#pragma unroll
        for (int j = 0; j < 2; j++)
          acc[i][j] = __builtin_amdgcn_mfma_f32_16x16x32_bf16(af[i], bfv[j], acc[i][j], 0, 0, 0);
    }
    __syncthreads();
    d ^= 1;
  }
#undef STAGE

  const bool doRope = (MODE == 1) && !vtr;
  const float ksc = (MODE == 1 && bx < 32) ? KLOG : 1.0f;

#pragma unroll
  for (int i = 0; i < 4; i++)
#pragma unroll
    for (int j = 0; j < 2; j++) {
      int col = col0 + wc * 32 + j * 16 + r16;
      int row0 = by * 128 + wr * 64 + i * 16 + g16 * 4;
      if (MODE == 1 && vtr) {
        short4v tv;
#pragma unroll
        for (int r = 0; r < 4; r++) tv[r] = (short)f2bf(acc[i][j][r]);
        *reinterpret_cast<short4v*>(&((ushort*)Cout)[(size_t)col * T_SEQ + row0]) = tv;
      } else if (doRope) {
        int pr = (col & 63) >> 1;
        bool ev = ((col & 1) == 0);
#pragma unroll
        for (int r = 0; r < 4; r++) {
          float a = acc[i][j][r];
          float b = __shfl_xor(a, 1);
          int t = row0 + r;
          float cv = fc[t * 32 + pr], sv = fs[t * 32 + pr];
          float v = ev ? (a * cv - b * sv) : (b * sv + a * cv);
          ((ushort*)Cout)[(size_t)t * ldc + col] = f2bf(v * ksc);
        }
      } else {
#pragma unroll
        for (int r = 0; r < 4; r++) {
          if constexpr (MODE == 0) ((float*)Cout)[(size_t)(row0 + r) * ldc + col] = acc[i][j][r];
          else                     ((ushort*)Cout)[(size_t)(row0 + r) * ldc + col] = f2bf(acc[i][j][r]);
        }
      }
    }
}

// Flash attention, swapped-operand 32x32, block-staged K/V in LDS,
// counted-vmcnt pipeline. (best measured config)
__global__ __launch_bounds__(512) void attn32(const ushort* __restrict__ Q,
                                              const ushort* __restrict__ K,
                                              const ushort* __restrict__ Vt,
                                              ushort* __restrict__ Y) {
  __shared__ ushort Klds[2][2][2048];
  __shared__ ushort Vlds[2][2][2048];
  __shared__ float oS[4][64][33];
  __shared__ float mS[4][32];
  __shared__ float sS[4][64];
  ushort (*Ot)[32][72] = reinterpret_cast<ushort (*)[32][72]>(&oS[0][0][0]);
  const int tid  = threadIdx.x;
  const int lane = tid & 63;
  const int wv   = tid >> 6;
  const int hh   = wv & 3;
  const int split = wv >> 2;
  const int g  = blockIdx.x & 7;
  const int qt = 63 - (blockIdx.x >> 3);
  const int h  = g * 4 + hh;
  const int q0 = qt << 5;
  const int l31 = lane & 31, hi = lane >> 5;
  const int hi8 = hi << 3, hi4 = hi << 2;
  const int qrow = q0 + l31;

  short8 qf[4];
#pragma unroll
  for (int s = 0; s < 4; s++)
    qf[s] = *reinterpret_cast<const short8*>(&Q[(size_t)qrow * C_DIM + h * HD + s * 16 + hi8]);

  f32x16 o[2] = { zero16(), zero16() };
  f32x16 sacc = zero16();
  float mrow = -1e30f;
  short8 ones8;
#pragma unroll
  for (int s = 0; s < 8; s++) ones8[s] = (short)0x3F80;

  auto pack8 = [&](const float* pp) -> short8 {
    unsigned wA, wB, wC, wD;
    asm("v_cvt_pk_bf16_f32 %0, %1, %2" : "=v"(wA) : "v"(pp[0]), "v"(pp[1]));
    asm("v_cvt_pk_bf16_f32 %0, %1, %2" : "=v"(wB) : "v"(pp[2]), "v"(pp[3]));
    asm("v_cvt_pk_bf16_f32 %0, %1, %2" : "=v"(wC) : "v"(pp[4]), "v"(pp[5]));
    asm("v_cvt_pk_bf16_f32 %0, %1, %2" : "=v"(wD) : "v"(pp[6]), "v"(pp[7]));
    asm("v_permlane32_swap_b32 %0, %1" : "+v"(wA), "+v"(wC));
    asm("v_permlane32_swap_b32 %0, %1" : "+v"(wB), "+v"(wD));
    int4v w4 = { (int)wA, (int)wB, (int)wC, (int)wD };
    return __builtin_bit_cast(short8, w4);
  };

  int wsr = (q0 - (WINDOW - 1)) >> 5;
  int wstart = (wsr < 1) ? 32 : (wsr << 5);
  int ntw = (q0 >= wstart) ? (((q0 - wstart) >> 5) + 1) : 0;
  const int NT = 1 + ntw;
  const int ihalf = (NT + 1) >> 1;

#define KBOF(i) ((i) == 0 ? 0 : wstart + ((i) - 1) * 32)
#define MSK(i)  ((i) == 0 || (KBOF(i) < q0 - 480) || (KBOF(i) == q0))

  const int sp_s = tid >> 8;
  const int kr = (tid >> 3) & 31, kc = tid & 7;
  const int vr = (tid >> 2) & 63, vc = tid & 3;
  const ushort* ksrc0 = K + (size_t)kr * (NKV * HD) + g * HD + ((kc ^ (kr & 7)) * 8);
  const ushort* vsrc0 = Vt + (size_t)(g * HD + vr) * T_SEQ + ((vc ^ ((vr >> 1) & 3)) * 8);
  ushort* kdst[2] = { &Klds[sp_s][0][(tid & 255) * 8], &Klds[sp_s][1][(tid & 255) * 8] };
  ushort* vdst[2] = { &Vlds[sp_s][0][(tid & 255) * 8], &Vlds[sp_s][1][(tid & 255) * 8] };

#define STAGE(dd, i0t, i1t)                                                    \
  {                                                                            \
    int idxs = sp_s ? (i1t) : (i0t);                                           \
    if (idxs > NT - 1) idxs = NT - 1;                                          \
    int kbs = KBOF(idxs);                                                      \
    gl_lds16(ksrc0 + (size_t)kbs * (NKV * HD), kdst[dd]);                      \
    gl_lds16(vsrc0 + kbs, vdst[dd]);                                           \
  }

#define PROCESS(dd, kb, domask)                                                    \
  {                                                                                \
    short8 kf0 = *reinterpret_cast<const short8*>(                                 \
        &Klds[split][dd][l31 * 64 + (((0 * 2 + hi) ^ (l31 & 7)) * 8)]);            \
    short8 kf1 = *reinterpret_cast<const short8*>(                                 \
        &Klds[split][dd][l31 * 64 + (((1 * 2 + hi) ^ (l31 & 7)) * 8)]);            \
    short8 kf2 = *reinterpret_cast<const short8*>(                                 \
        &Klds[split][dd][l31 * 64 + (((2 * 2 + hi) ^ (l31 & 7)) * 8)]);            \
    short8 kf3 = *reinterpret_cast<const short8*>(                                 \
        &Klds[split][dd][l31 * 64 + (((3 * 2 + hi) ^ (l31 & 7)) * 8)]);            \
    f32x16 sa = zero16();                                                          \
    __builtin_amdgcn_s_setprio(1);                                                 \
    sa = __builtin_amdgcn_mfma_f32_32x32x16_bf16(kf0, qf[0], sa, 0, 0, 0);         \
    sa = __builtin_amdgcn_mfma_f32_32x32x16_bf16(kf1, qf[1], sa, 0, 0, 0);         \
    sa = __builtin_amdgcn_mfma_f32_32x32x16_bf16(kf2, qf[2], sa, 0, 0, 0);         \
    sa = __builtin_amdgcn_mfma_f32_32x32x16_bf16(kf3, qf[3], sa, 0, 0, 0);         \
    __builtin_amdgcn_s_setprio(0);                                                 \
    float p[16];                                                                   \
    _Pragma("unroll") for (int r = 0; r < 16; r++) p[r] = sa[r];                   \
    if (domask) {                                                                  \
      _Pragma("unroll") for (int r = 0; r < 16; r++) {                             \
        int kidx = (kb) + (r & 3) + 8 * (r >> 2) + hi4;                            \
        bool ok = ((kidx <= qrow) && (kidx >= qrow - (WINDOW - 1))) || (kidx < NGLOB); \
        p[r] = ok ? p[r] : -1e30f;                                                 \
      }                                                                            \
    }                                                                              \
    float m0 = max3f(p[0], p[1], p[2]);                                            \
    float m1 = max3f(p[3], p[4], p[5]);                                            \
    float m2 = max3f(p[6], p[7], p[8]);                                            \
    float m3 = max3f(p[9], p[10], p[11]);                                          \
    float m4 = max3f(p[12], p[13], p[14]);                                         \
    float tmax = fmaxf(max3f(m0, m1, m2), max3f(m3, m4, p[15]));                   \
    float pmax = fmaxf(tmax, __shfl_xor(tmax, 32));                                \
    if (!__all(pmax <= mrow + 8.0f)) {                                             \
      float mnew = fmaxf(mrow, pmax);                                              \
      float corr = exp2f(mrow - mnew);                                             \
      sacc[0] *= corr;                                                             \
      _Pragma("unroll") for (int r = 0; r < 16; r++) { o[0][r] *= corr; o[1][r] *= corr; } \
      mrow = mnew;                                                                 \
    }                                                                              \
    _Pragma("unroll") for (int r = 0; r < 16; r++) p[r] = exp2f(p[r] - mrow);      \
    short8 pb0 = pack8(&p[0]);                                                     \
    short8 pb1 = pack8(&p[8]);                                                     \
    short8 v0 = *reinterpret_cast<const short8*>(                                  \
        &Vlds[split][dd][(0 * 32 + l31) * 32 + (((0 * 2 + hi) ^ ((l31 >> 1) & 3)) * 8)]); \
    short8 v1 = *reinterpret_cast<const short8*>(                                  \
        &Vlds[split][dd][(0 * 32 + l31) * 32 + (((1 * 2 + hi) ^ ((l31 >> 1) & 3)) * 8)]); \
    short8 v2 = *reinterpret_cast<const short8*>(                                  \
        &Vlds[split][dd][(1 * 32 + l31) * 32 + (((0 * 2 + hi) ^ (((32 + l31) >> 1) & 3)) * 8)]); \
    short8 v3 = *reinterpret_cast<const short8*>(                                  \
        &Vlds[split][dd][(1 * 32 + l31) * 32 + (((1 * 2 + hi) ^ (((32 + l31) >> 1) & 3)) * 8)]); \
    __builtin_amdgcn_s_setprio(1);                                                 \
    sacc = __builtin_amdgcn_mfma_f32_32x32x16_bf16(ones8, pb0, sacc, 0, 0, 0);     \
    sacc = __builtin_amdgcn_mfma_f32_32x32x16_bf16(ones8, pb1, sacc, 0, 0, 0);     \
    o[0] = __builtin_amdgcn_mfma_f32_32x32x16_bf16(v0, pb0, o[0], 0, 0, 0);        \
    o[0] = __builtin_amdgcn_mfma_f32_32x32x16_bf16(v1, pb1, o[0], 0, 0, 0);        \
    o[1] = __builtin_amdgcn_mfma_f32_32x32x16_bf16(v2, pb0, o[1], 0, 0, 0);        \
    o[1] = __builtin_amdgcn_mfma_f32_32x32x16_bf16(v3, pb1, o[1], 0, 0, 0);        \
    __builtin_amdgcn_s_setprio(0);                                                 \
  }

  STAGE(0, 0, ihalf);
  asm volatile("s_waitcnt vmcnt(0)" ::: "memory");
  __builtin_amdgcn_s_barrier();
  int d = 0;
  for (int it = 0; it < ihalf; ++it) {
    if (it + 1 < ihalf) {
      STAGE(d ^ 1, it + 1, ihalf + it + 1);
      asm volatile("s_waitcnt vmcnt(2)" ::: "memory");
    } else {
      asm volatile("s_waitcnt vmcnt(0)" ::: "memory");
    }
    __builtin_amdgcn_s_barrier();
    int idx = split ? (ihalf + it) : it;
    if (idx < NT) {
      int kb = KBOF(idx);
      PROCESS(d, kb, MSK(idx));
    }
    asm volatile("" ::: "memory");
    __builtin_amdgcn_s_barrier();
    d ^= 1;
  }
#undef STAGE
#undef PROCESS
#undef KBOF
#undef MSK

  float ssum = sacc[0];

  if (split == 1) {
    if (hi == 0) mS[hh][l31] = mrow;
    sS[hh][lane] = ssum;
#pragma unroll
    for (int ntl = 0; ntl < 2; ntl++)
#pragma unroll
      for (int r = 0; r < 16; r++) oS[hh][lane][ntl * 16 + r] = o[ntl][r];
  }
  __syncthreads();

  float inv = 0.f;
  if (split == 0) {
    float mB = mS[hh][l31];
    float sB = sS[hh][lane];
    float mN = fmaxf(mrow, mB);
    float cA = exp2f(mrow - mN), cB = exp2f(mB - mN);
    ssum = ssum * cA + sB * cB;
#pragma unroll
    for (int ntl = 0; ntl < 2; ntl++)
#pragma unroll
      for (int r = 0; r < 16; r++)
        o[ntl][r] = o[ntl][r] * cA + oS[hh][lane][ntl * 16 + r] * cB;
    inv = 1.0f / ssum;
  }
  __syncthreads();

  if (split == 0) {
#pragma unroll
    for (int ntl = 0; ntl < 2; ntl++)
#pragma unroll
      for (int r = 0; r < 16; r++) {
        int dim = ntl * 32 + (r & 3) + 8 * (r >> 2) + hi4;
        Ot[hh][l31][dim] = f2bf(o[ntl][r] * inv);
      }
  }
  __syncthreads();

  if (split == 0) {
    int qq = lane >> 1, hf = lane & 1;
#pragma unroll
    for (int c = 0; c < 4; c++) {
      short8 vv = *reinterpret_cast<const short8*>(&Ot[hh][qq][hf * 32 + c * 8]);
      *reinterpret_cast<short8*>(&Y[(size_t)(q0 + qq) * C_DIM + h * HD + hf * 32 + c * 8]) = vv;
    }
  }
}

extern "C" void kernel_launch(void* const* d_in, const int* in_sizes, int n_in,
                              void* d_out, int out_size, void* d_ws, size_t ws_size,
                              hipStream_t stream) {
  const float* x  = (const float*)d_in[0];
  const float* fc = (const float*)d_in[1];
  const float* fs = (const float*)d_in[2];
  const float* wq = (const float*)d_in[3];
  const float* wk = (const float*)d_in[4];
  const float* wv = (const float*)d_in[5];
  const float* wo = (const float*)d_in[6];
  float* out = (float*)d_out;

  const size_t SZ_X = (size_t)T_SEQ * C_DIM;
  const size_t SZ_W = (size_t)(NKV * HD) * C_DIM;

  ushort* xb  = (ushort*)d_ws;
  ushort* wqb = xb  + SZ_X;
  ushort* wkb = wqb + SZ_X;
  ushort* wvb = wkb + SZ_W;
  ushort* wob = wvb + SZ_W;
  ushort* Qb  = wob + SZ_X;
  ushort* Kb  = Qb  + SZ_X;
  ushort* Vt  = Kb  + SZ_W;
  ushort* Yb  = Vt  + SZ_W;

  cvt_all<<<1024, 256, 0, stream>>>(x,  xb,  (int)(SZ_X / 8),
                                    wq, wqb, (int)(SZ_X / 8),
                                    wk, wkb, (int)(SZ_W / 8),
                                    wv, wvb, (int)(SZ_W / 8),
                                    wo, wob, (int)(SZ_X / 8));

  // fused QKV projection + RoPE(Q,K) + Q-scale; V written pre-transposed
  gemm2p<1><<<dim3(48, 16), 256, 0, stream>>>(xb, wqb, wkb, wvb, Qb, Kb, Vt, fc, fs, C_DIM);

  attn32<<<512, 512, 0, stream>>>(Qb, Kb, Vt, Yb);

  // output projection, f32 out
  gemm2p<0><<<dim3(32, 16), 256, 0, stream>>>(Yb, wob, nullptr, nullptr, out, nullptr, nullptr,
                                              fc, fs, C_DIM);
}